// Round 6
// baseline (187.125 us; speedup 1.0000x reference)
//
#include <hip/hip_runtime.h>
#include <stdint.h>

// Problem constants (from reference)
#define NB   4      // batch
#define CC   256    // channels (K)
#define WR   60     // cells per row/col
#define MM   3600   // HR*WR (M and N of the GEMM)
#define HH   480
#define WW   480
#define GS   8
#define MT   29     // ceil(3600/128) tiles per side
#define NBLK (MT * MT * NB)      // gemm grid size = 3364
#define PREPB 57                 // ceil(NB*MM / 256) blocks carrying prep work

typedef float f32x4 __attribute__((ext_vector_type(4)));

// ---------------------------------------------------------------------------
// Kernel 1: pack desc[b][c][m] (f32) into MFMA-fragment-ordered fp8-e4m3:
//   packed[b][mtile][kt][ slot = (h*4 + t)*64 + lane ][8 fp8]
// where m = mtile*128 + h*64 + t*16 + (lane&15), k = kt*32 + (lane>>4)*8 + e.
// Each wave-fragment (t,kt,h) is a contiguous coalesced 512-B line -> the
// GEMM loads fragments STRAIGHT INTO REGISTERS (global_load_dwordx2), no LDS.
// Tail rows zero-filled. FUSED: blocks 0..56 do per-cell prep; block 0
// zeroes loss+counter.
// ---------------------------------------------------------------------------
__global__ __launch_bounds__(256) void pack_prep(
    const float* __restrict__ d1, const float* __restrict__ d2,
    const float* __restrict__ homo, const float* __restrict__ vis,
    unsigned char* __restrict__ p1, unsigned char* __restrict__ p2,
    float2* __restrict__ wg, float* __restrict__ vmarr,
    float* __restrict__ vm_part, float* __restrict__ loss_sum,
    unsigned* __restrict__ counter) {
  __shared__ float tile[32][132];   // [k_local][m_local]; rows 528B (16B-aligned)
  int kt = blockIdx.x, mtile = blockIdx.y, z = blockIdx.z;
  int bid = kt + 8 * (mtile + MT * z);
  int b = z & 3;
  const float* src = ((z >> 2) ? d2 : d1) + (size_t)b * CC * MM + (size_t)(kt * 32) * MM;
  unsigned char* dst = ((z >> 2) ? p2 : p1) + ((size_t)(b * MT + mtile) * 8 + kt) * 4096;
  int tid = threadIdx.x;

  if (bid == 0 && tid == 0) { loss_sum[0] = 0.f; *counter = 0u; }

  // coalesced read: 32 k-rows x 128 m (float4 along m)
#pragma unroll
  for (int pass = 0; pass < 4; ++pass) {
    int cid = pass * 256 + tid;          // [0,1024)
    int c = cid >> 5, m4 = (cid & 31) * 4;
    int gm = mtile * 128 + m4;
    float4 v;
    if (gm + 3 < MM) {
      v = *(const float4*)(src + (size_t)c * MM + gm);
    } else {
      v.x = (gm     < MM) ? src[(size_t)c * MM + gm]     : 0.f;
      v.y = (gm + 1 < MM) ? src[(size_t)c * MM + gm + 1] : 0.f;
      v.z = (gm + 2 < MM) ? src[(size_t)c * MM + gm + 2] : 0.f;
      v.w = (gm + 3 < MM) ? src[(size_t)c * MM + gm + 3] : 0.f;
    }
    *(float4*)&tile[c][m4] = v;
  }
  __syncthreads();

  // fragment-order write: 512 slots of 8B; slot s = ((h*4+t)*64 + lane)
#pragma unroll
  for (int pass = 0; pass < 2; ++pass) {
    int s = pass * 256 + tid;            // [0,512)
    int lane = s & 63, tt = (s >> 6) & 3, h = s >> 8;
    int m_local = h * 64 + tt * 16 + (lane & 15);
    int k_local = (lane >> 4) * 8;
    int w01 = 0, w23 = 0;
    if (mtile * 128 + m_local < MM) {
      float f0 = tile[k_local + 0][m_local], f1 = tile[k_local + 1][m_local];
      float f2 = tile[k_local + 2][m_local], f3 = tile[k_local + 3][m_local];
      float f4 = tile[k_local + 4][m_local], f5 = tile[k_local + 5][m_local];
      float f6 = tile[k_local + 6][m_local], f7 = tile[k_local + 7][m_local];
      w01 = __builtin_amdgcn_cvt_pk_fp8_f32(f0, f1, 0, false);
      w01 = __builtin_amdgcn_cvt_pk_fp8_f32(f2, f3, w01, true);
      w23 = __builtin_amdgcn_cvt_pk_fp8_f32(f4, f5, 0, false);
      w23 = __builtin_amdgcn_cvt_pk_fp8_f32(f6, f7, w23, true);
    }
    ((int2*)dst)[s] = make_int2(w01, w23);
  }

  // ---- fused prep (blocks 0..56 only; block-uniform branch) ----
  if (bid < PREPB) {
    int idx = bid * 256 + tid;
    float p = 0.f;
    if (idx < NB * MM) {
      int bb = idx / MM, cell = idx - bb * MM;
      int h1 = cell / WR, w1 = cell - h1 * WR;
      float gx = (float)(w1 * GS + GS / 2);
      float gy = (float)(h1 * GS + GS / 2);
      const float* Hm = homo + bb * 9;
      float X = Hm[0] * gx + Hm[1] * gy + Hm[2];
      float Y = Hm[3] * gx + Hm[4] * gy + Hm[5];
      float Z = Hm[6] * gx + Hm[7] * gy + Hm[8];
      wg[idx] = make_float2(X / Z, Y / Z);
      const float* v = vis + (size_t)bb * HH * WW + (size_t)(h1 * GS) * WW + w1 * GS;
      float prod = 1.f;
#pragma unroll
      for (int rr = 0; rr < GS; ++rr) {
        const float4* rp = (const float4*)(v + (size_t)rr * WW);
        float4 a = rp[0], c = rp[1];
        prod *= a.x * a.y * a.z * a.w;
        prod *= c.x * c.y * c.z * c.w;
      }
      vmarr[idx] = prod;
      p = prod;
    }
#pragma unroll
    for (int off = 32; off; off >>= 1) p += __shfl_down(p, off, 64);
    __syncthreads();                      // tile LDS reuse safety
    if ((tid & 63) == 0) ((float*)tile)[tid >> 6] = p;
    __syncthreads();
    if (tid == 0)
      vm_part[bid] = ((float*)tile)[0] + ((float*)tile)[1] +
                     ((float*)tile)[2] + ((float*)tile)[3];
  }
}

// ---------------------------------------------------------------------------
// Kernel 2: fp8 MFMA GEMM + hinge loss, NO LDS, NO K-loop barriers.
// Fragments are global-loaded straight into registers (each wave's operand
// line is contiguous 512 B -> one global_load_dwordx2 per lane), register
// double-buffered with prefetch distance 1. The compiler interleaves MFMA
// with buffer loads using fine-grained vmcnt(N) — the pipelining that the
// global_load_lds + __syncthreads structure (rounds 2-5) cannot express.
// 4 waves/SIMD (launch_bounds(256,4)) provide TLP over residual L2 latency.
// ---------------------------------------------------------------------------
__global__ __launch_bounds__(256, 4) void hinge_gemm(
    const unsigned char* __restrict__ Ap, const unsigned char* __restrict__ Bp,
    const float2* __restrict__ wg, const float* __restrict__ vmarr,
    const float* __restrict__ vm_part, float* __restrict__ loss_sum,
    unsigned* __restrict__ counter, float* __restrict__ out) {
  __shared__ float partial[4];

  int b = blockIdx.z, mtile = blockIdx.y, ntile = blockIdx.x;
  int tid = threadIdx.x, lane = tid & 63, w = tid >> 6;
  int quad = lane >> 4, r = lane & 15;
  int wave_m = w >> 1, wave_n = w & 1;

  // per-lane fragment base: fragment(t,kt) at base + kt*4096 + t*512
  const char* Af = (const char*)Ap + ((size_t)(b * MT + mtile) * 8) * 4096
                   + wave_m * 2048 + lane * 8;
  const char* Bf = (const char*)Bp + ((size_t)(b * MT + ntile) * 8) * 4096
                   + wave_n * 2048 + lane * 8;

  f32x4 acc[4][4];
#pragma unroll
  for (int i = 0; i < 4; ++i)
#pragma unroll
    for (int j = 0; j < 4; ++j)
#pragma unroll
      for (int k = 0; k < 4; ++k) acc[i][j][k] = 0.f;

  long a0[4], b0[4], a1[4], b1[4];
#pragma unroll
  for (int t = 0; t < 4; ++t) {
    a0[t] = *(const long*)(Af + t * 512);
    b0[t] = *(const long*)(Bf + t * 512);
  }

#pragma unroll
  for (int kt = 0; kt < 8; ++kt) {
    if (kt < 7) {   // prefetch kt+1 fragments into the shadow registers
      const char* an = Af + (kt + 1) * 4096;
      const char* bn = Bf + (kt + 1) * 4096;
#pragma unroll
      for (int t = 0; t < 4; ++t) {
        a1[t] = *(const long*)(an + t * 512);
        b1[t] = *(const long*)(bn + t * 512);
      }
    }
#pragma unroll
    for (int mt = 0; mt < 4; ++mt)
#pragma unroll
      for (int nt = 0; nt < 4; ++nt)
        acc[mt][nt] = __builtin_amdgcn_mfma_f32_16x16x32_fp8_fp8(
            a0[mt], b0[nt], acc[mt][nt], 0, 0, 0);
#pragma unroll
    for (int t = 0; t < 4; ++t) { a0[t] = a1[t]; b0[t] = b1[t]; }
  }

  // Epilogue. C/D layout: col(n) = lane&15, row(m) = quad*4 + reg.
  // Tail m-rows are zero-padded in Ap -> dot=0 -> hinge=0; no m-guard needed.
  float gxv[16], gyv[16];
#pragma unroll
  for (int mt = 0; mt < 4; ++mt)
#pragma unroll
    for (int reg = 0; reg < 4; ++reg) {
      int gm = mtile * 128 + wave_m * 64 + mt * 16 + quad * 4 + reg;
      float gmf = (float)gm;
      float h1 = floorf(fmaf(gmf, (1.0f / 60.0f), (1.0f / 120.0f)));
      float w1 = fmaf(h1, -60.f, gmf);
      gxv[mt * 4 + reg] = fmaf(w1, 8.f, 4.f);
      gyv[mt * 4 + reg] = fmaf(h1, 8.f, 4.f);
    }

  float sum = 0.f;
  const float2* wgb = wg + (size_t)b * MM;
  const float*  vmb = vmarr + (size_t)b * MM;
#pragma unroll
  for (int nt = 0; nt < 4; ++nt) {
    int gn = ntile * 128 + wave_n * 64 + nt * 16 + r;
    bool nok = gn < MM;
    float2 wgv = nok ? wgb[gn] : make_float2(1e9f, 1e9f);
    float  vmv = nok ? vmb[gn] : 0.f;
#pragma unroll
    for (int mt = 0; mt < 4; ++mt)
#pragma unroll
      for (int reg = 0; reg < 4; ++reg) {
        float dot = acc[mt][nt][reg];
        float dx = gxv[mt * 4 + reg] - wgv.x;
        float dy = gyv[mt * 4 + reg] - wgv.y;
        float d2 = fmaf(dx, dx, dy * dy);
        float a = (d2 <= 56.25f) ? (1.0f - dot) : (dot - 0.2f);
        sum = fmaf(vmv, fmaxf(a, 0.f), sum);
      }
  }
#pragma unroll
  for (int off = 32; off; off >>= 1) sum += __shfl_down(sum, off, 64);
  if (lane == 0) partial[w] = sum;
  __syncthreads();
  if (tid == 0) {
    float bs = partial[0] + partial[1] + partial[2] + partial[3];
    atomicAdd(loss_sum, bs);
    __threadfence();
    unsigned old = atomicAdd(counter, 1u);
    if (old == (unsigned)NBLK - 1u) {     // last block: finalize
      float vs = 0.f;
      for (int i = 0; i < PREPB; ++i) vs += vm_part[i];
      float lt = atomicAdd(loss_sum, 0.f);  // atomic read: all adds visible
      out[0] = lt / ((float)MM * vs);
    }
  }
}

extern "C" void kernel_launch(void* const* d_in, const int* in_sizes, int n_in,
                              void* d_out, int out_size, void* d_ws, size_t ws_size,
                              hipStream_t stream) {
  const float* desc1 = (const float*)d_in[0];
  const float* desc2 = (const float*)d_in[1];
  const float* homo  = (const float*)d_in[2];
  const float* vis   = (const float*)d_in[3];
  float* out = (float*)d_out;

  char* ws = (char*)d_ws;
  // packed size per desc: 4 * 29 * 8 * 4096 B = 3,801,088 B
  unsigned char* Ap = (unsigned char*)ws;
  unsigned char* Bp = (unsigned char*)(ws + 3801088);
  float2*   wg      = (float2*)(ws + 7602176);           // 115,200 B
  float*    vm      = (float*) (ws + 7717376);           //  57,600 B
  float*    vm_part = (float*) (ws + 7774976);           // 57 * 4 B
  float*    sums    = (float*) (ws + 7775232);           // loss accumulator
  unsigned* counter = (unsigned*)(ws + 7775236);

  dim3 pgrid(8, MT, 2 * NB);   // kt x mtile x (desc,b); fused prep + zero-init
  pack_prep<<<pgrid, 256, 0, stream>>>(desc1, desc2, homo, vis, Ap, Bp,
                                       wg, vm, vm_part, sums, counter);

  dim3 ggrid(MT, MT, NB);
  hinge_gemm<<<ggrid, 256, 0, stream>>>(Ap, Bp, wg, vm, vm_part,
                                        sums, counter, out);
}

// Round 7
// 121.235 us; speedup vs baseline: 1.5435x; 1.5435x over previous
//
#include <hip/hip_runtime.h>
#include <stdint.h>

// Problem constants (from reference)
#define NB   4      // batch
#define CC   256    // channels (K)
#define WR   60     // cells per row/col
#define MM   3600   // HR*WR (M and N of the GEMM)
#define HH   480
#define WW   480
#define GS   8
#define MT   29     // ceil(3600/128) tiles per side
#define NBLK (MT * MT * NB)      // gemm grid size = 3364
#define PREPB 57                 // ceil(NB*MM / 256) blocks carrying prep work

typedef float f32x4 __attribute__((ext_vector_type(4)));

// ---------------------------------------------------------------------------
// Kernel 1: pack desc[b][c][m] (f32) into MFMA-fragment-ordered fp8-e4m3:
//   packed[b][mtile][kt][ slot = (h*4 + t)*64 + lane ][8 fp8]
// where m = mtile*128 + h*64 + t*16 + (lane&15), k = kt*32 + (lane>>4)*8 + e.
// Each wave-fragment (t,kt,h) is a contiguous coalesced 512-B line -> the
// GEMM loads fragments STRAIGHT INTO REGISTERS, no LDS. Tail rows
// zero-filled. FUSED: blocks 0..56 do per-cell prep (homography warp,
// vis 8x8 product, per-block vm partials).
// ---------------------------------------------------------------------------
__global__ __launch_bounds__(256) void pack_prep(
    const float* __restrict__ d1, const float* __restrict__ d2,
    const float* __restrict__ homo, const float* __restrict__ vis,
    unsigned char* __restrict__ p1, unsigned char* __restrict__ p2,
    float2* __restrict__ wg, float* __restrict__ vmarr,
    float* __restrict__ vm_part) {
  __shared__ float tile[32][132];   // [k_local][m_local]; rows 528B (16B-aligned)
  int kt = blockIdx.x, mtile = blockIdx.y, z = blockIdx.z;
  int bid = kt + 8 * (mtile + MT * z);
  int b = z & 3;
  const float* src = ((z >> 2) ? d2 : d1) + (size_t)b * CC * MM + (size_t)(kt * 32) * MM;
  unsigned char* dst = ((z >> 2) ? p2 : p1) + ((size_t)(b * MT + mtile) * 8 + kt) * 4096;
  int tid = threadIdx.x;

  // coalesced read: 32 k-rows x 128 m (float4 along m)
#pragma unroll
  for (int pass = 0; pass < 4; ++pass) {
    int cid = pass * 256 + tid;          // [0,1024)
    int c = cid >> 5, m4 = (cid & 31) * 4;
    int gm = mtile * 128 + m4;
    float4 v;
    if (gm + 3 < MM) {
      v = *(const float4*)(src + (size_t)c * MM + gm);
    } else {
      v.x = (gm     < MM) ? src[(size_t)c * MM + gm]     : 0.f;
      v.y = (gm + 1 < MM) ? src[(size_t)c * MM + gm + 1] : 0.f;
      v.z = (gm + 2 < MM) ? src[(size_t)c * MM + gm + 2] : 0.f;
      v.w = (gm + 3 < MM) ? src[(size_t)c * MM + gm + 3] : 0.f;
    }
    *(float4*)&tile[c][m4] = v;
  }
  __syncthreads();

  // fragment-order write: 512 slots of 8B; slot s = ((h*4+t)*64 + lane)
#pragma unroll
  for (int pass = 0; pass < 2; ++pass) {
    int s = pass * 256 + tid;            // [0,512)
    int lane = s & 63, tt = (s >> 6) & 3, h = s >> 8;
    int m_local = h * 64 + tt * 16 + (lane & 15);
    int k_local = (lane >> 4) * 8;
    int w01 = 0, w23 = 0;
    if (mtile * 128 + m_local < MM) {
      float f0 = tile[k_local + 0][m_local], f1 = tile[k_local + 1][m_local];
      float f2 = tile[k_local + 2][m_local], f3 = tile[k_local + 3][m_local];
      float f4 = tile[k_local + 4][m_local], f5 = tile[k_local + 5][m_local];
      float f6 = tile[k_local + 6][m_local], f7 = tile[k_local + 7][m_local];
      w01 = __builtin_amdgcn_cvt_pk_fp8_f32(f0, f1, 0, false);
      w01 = __builtin_amdgcn_cvt_pk_fp8_f32(f2, f3, w01, true);
      w23 = __builtin_amdgcn_cvt_pk_fp8_f32(f4, f5, 0, false);
      w23 = __builtin_amdgcn_cvt_pk_fp8_f32(f6, f7, w23, true);
    }
    ((int2*)dst)[s] = make_int2(w01, w23);
  }

  // ---- fused prep (blocks 0..56 only; block-uniform branch) ----
  if (bid < PREPB) {
    int idx = bid * 256 + tid;
    float p = 0.f;
    if (idx < NB * MM) {
      int bb = idx / MM, cell = idx - bb * MM;
      int h1 = cell / WR, w1 = cell - h1 * WR;
      float gx = (float)(w1 * GS + GS / 2);
      float gy = (float)(h1 * GS + GS / 2);
      const float* Hm = homo + bb * 9;
      float X = Hm[0] * gx + Hm[1] * gy + Hm[2];
      float Y = Hm[3] * gx + Hm[4] * gy + Hm[5];
      float Z = Hm[6] * gx + Hm[7] * gy + Hm[8];
      wg[idx] = make_float2(X / Z, Y / Z);
      const float* v = vis + (size_t)bb * HH * WW + (size_t)(h1 * GS) * WW + w1 * GS;
      float prod = 1.f;
#pragma unroll
      for (int rr = 0; rr < GS; ++rr) {
        const float4* rp = (const float4*)(v + (size_t)rr * WW);
        float4 a = rp[0], c = rp[1];
        prod *= a.x * a.y * a.z * a.w;
        prod *= c.x * c.y * c.z * c.w;
      }
      vmarr[idx] = prod;
      p = prod;
    }
#pragma unroll
    for (int off = 32; off; off >>= 1) p += __shfl_down(p, off, 64);
    __syncthreads();                      // tile LDS reuse safety
    if ((tid & 63) == 0) ((float*)tile)[tid >> 6] = p;
    __syncthreads();
    if (tid == 0)
      vm_part[bid] = ((float*)tile)[0] + ((float*)tile)[1] +
                     ((float*)tile)[2] + ((float*)tile)[3];
  }
}

// ---------------------------------------------------------------------------
// Kernel 2: fp8 MFMA GEMM + hinge loss. NO LDS staging, NO K-loop barriers,
// and — the round-7 fix — NO contended atomics: rounds 1-6 were bound by
// serialized same-cacheline device atomicAdds (2 per block x 3364 blocks
// ~ 115-130 us; 1 per block ~ 66-71 us — matches every measured round).
// Each block now writes its partial to a private slot; a tiny finalize
// kernel reduces them.
// ---------------------------------------------------------------------------
__global__ __launch_bounds__(256, 4) void hinge_gemm(
    const unsigned char* __restrict__ Ap, const unsigned char* __restrict__ Bp,
    const float2* __restrict__ wg, const float* __restrict__ vmarr,
    float* __restrict__ block_part) {
  __shared__ float partial[4];

  int b = blockIdx.z, mtile = blockIdx.y, ntile = blockIdx.x;
  int tid = threadIdx.x, lane = tid & 63, w = tid >> 6;
  int quad = lane >> 4, r = lane & 15;
  int wave_m = w >> 1, wave_n = w & 1;

  // per-lane fragment base: fragment(t,kt) at base + kt*4096 + t*512
  const char* Af = (const char*)Ap + ((size_t)(b * MT + mtile) * 8) * 4096
                   + wave_m * 2048 + lane * 8;
  const char* Bf = (const char*)Bp + ((size_t)(b * MT + ntile) * 8) * 4096
                   + wave_n * 2048 + lane * 8;

  f32x4 acc[4][4];
#pragma unroll
  for (int i = 0; i < 4; ++i)
#pragma unroll
    for (int j = 0; j < 4; ++j)
#pragma unroll
      for (int k = 0; k < 4; ++k) acc[i][j][k] = 0.f;

  long a0[4], b0[4], a1[4], b1[4];
#pragma unroll
  for (int t = 0; t < 4; ++t) {
    a0[t] = *(const long*)(Af + t * 512);
    b0[t] = *(const long*)(Bf + t * 512);
  }

#pragma unroll
  for (int kt = 0; kt < 8; ++kt) {
    if (kt < 7) {   // prefetch kt+1 fragments into the shadow registers
      const char* an = Af + (kt + 1) * 4096;
      const char* bn = Bf + (kt + 1) * 4096;
#pragma unroll
      for (int t = 0; t < 4; ++t) {
        a1[t] = *(const long*)(an + t * 512);
        b1[t] = *(const long*)(bn + t * 512);
      }
    }
#pragma unroll
    for (int mt = 0; mt < 4; ++mt)
#pragma unroll
      for (int nt = 0; nt < 4; ++nt)
        acc[mt][nt] = __builtin_amdgcn_mfma_f32_16x16x32_fp8_fp8(
            a0[mt], b0[nt], acc[mt][nt], 0, 0, 0);
#pragma unroll
    for (int t = 0; t < 4; ++t) { a0[t] = a1[t]; b0[t] = b1[t]; }
  }

  // Epilogue. C/D layout: col(n) = lane&15, row(m) = quad*4 + reg.
  // Tail m-rows are zero-padded in Ap -> dot=0 -> hinge=0; no m-guard needed.
  float gxv[16], gyv[16];
#pragma unroll
  for (int mt = 0; mt < 4; ++mt)
#pragma unroll
    for (int reg = 0; reg < 4; ++reg) {
      int gm = mtile * 128 + wave_m * 64 + mt * 16 + quad * 4 + reg;
      float gmf = (float)gm;
      float h1 = floorf(fmaf(gmf, (1.0f / 60.0f), (1.0f / 120.0f)));
      float w1 = fmaf(h1, -60.f, gmf);
      gxv[mt * 4 + reg] = fmaf(w1, 8.f, 4.f);
      gyv[mt * 4 + reg] = fmaf(h1, 8.f, 4.f);
    }

  float sum = 0.f;
  const float2* wgb = wg + (size_t)b * MM;
  const float*  vmb = vmarr + (size_t)b * MM;
#pragma unroll
  for (int nt = 0; nt < 4; ++nt) {
    int gn = ntile * 128 + wave_n * 64 + nt * 16 + r;
    bool nok = gn < MM;
    float2 wgv = nok ? wgb[gn] : make_float2(1e9f, 1e9f);
    float  vmv = nok ? vmb[gn] : 0.f;
#pragma unroll
    for (int mt = 0; mt < 4; ++mt)
#pragma unroll
      for (int reg = 0; reg < 4; ++reg) {
        float dot = acc[mt][nt][reg];
        float dx = gxv[mt * 4 + reg] - wgv.x;
        float dy = gyv[mt * 4 + reg] - wgv.y;
        float d2 = fmaf(dx, dx, dy * dy);
        float a = (d2 <= 56.25f) ? (1.0f - dot) : (dot - 0.2f);
        sum = fmaf(vmv, fmaxf(a, 0.f), sum);
      }
  }
#pragma unroll
  for (int off = 32; off; off >>= 1) sum += __shfl_down(sum, off, 64);
  if (lane == 0) partial[w] = sum;
  __syncthreads();
  if (tid == 0) {
    int fbid = ntile + MT * (mtile + MT * b);
    block_part[fbid] = partial[0] + partial[1] + partial[2] + partial[3];
  }
}

// ---------------------------------------------------------------------------
// Kernel 3: reduce 3364 block partials + 57 vm partials; write output.
// ---------------------------------------------------------------------------
__global__ __launch_bounds__(256) void finalize_k(
    const float* __restrict__ block_part, const float* __restrict__ vm_part,
    float* __restrict__ out) {
  __shared__ float red[8];
  int tid = threadIdx.x;
  float s = 0.f, v = 0.f;
  for (int i = tid; i < NBLK; i += 256) s += block_part[i];
  if (tid < PREPB) v = vm_part[tid];
#pragma unroll
  for (int off = 32; off; off >>= 1) {
    s += __shfl_down(s, off, 64);
    v += __shfl_down(v, off, 64);
  }
  if ((tid & 63) == 0) { red[tid >> 6] = s; red[4 + (tid >> 6)] = v; }
  __syncthreads();
  if (tid == 0) {
    float S = red[0] + red[1] + red[2] + red[3];
    float V = red[4] + red[5] + red[6] + red[7];
    out[0] = S / ((float)MM * V);
  }
}

extern "C" void kernel_launch(void* const* d_in, const int* in_sizes, int n_in,
                              void* d_out, int out_size, void* d_ws, size_t ws_size,
                              hipStream_t stream) {
  const float* desc1 = (const float*)d_in[0];
  const float* desc2 = (const float*)d_in[1];
  const float* homo  = (const float*)d_in[2];
  const float* vis   = (const float*)d_in[3];
  float* out = (float*)d_out;

  char* ws = (char*)d_ws;
  // packed size per desc: 4 * 29 * 8 * 4096 B = 3,801,088 B
  unsigned char* Ap = (unsigned char*)ws;
  unsigned char* Bp = (unsigned char*)(ws + 3801088);
  float2* wg         = (float2*)(ws + 7602176);          // 115,200 B
  float*  vm         = (float*) (ws + 7717376);          //  57,600 B
  float*  vm_part    = (float*) (ws + 7774976);          // 57 * 4 B
  float*  block_part = (float*) (ws + 7775232);          // 3364 * 4 B

  dim3 pgrid(8, MT, 2 * NB);   // kt x mtile x (desc,b); fused prep
  pack_prep<<<pgrid, 256, 0, stream>>>(desc1, desc2, homo, vis, Ap, Bp,
                                       wg, vm, vm_part);

  dim3 ggrid(MT, MT, NB);
  hinge_gemm<<<ggrid, 256, 0, stream>>>(Ap, Bp, wg, vm, block_part);

  finalize_k<<<1, 256, 0, stream>>>(block_part, vm_part, out);
}